// Round 5
// baseline (375.144 us; speedup 1.0000x reference)
//
#include <hip/hip_runtime.h>
#include <hip/hip_bf16.h>

// ---------------- problem constants ----------------
#define N_NODES 4096
#define NE      32768           // raw edges
#define E_TOT   (NE + N_NODES)  // + self loops = 36864
#define IN_FEAT 256
#define HID     64
#define IN_HEAD 64
#define F1      4096            // IN_HEAD*HID
#define OUT_HEAD 5
#define OUT_FEAT 128
#define F2      640             // OUT_HEAD*OUT_FEAT
#define NEG_SLOPE 0.2f
#define EPS_A   1e-16f

typedef __bf16 bf16;
typedef bf16 bf16x8 __attribute__((ext_vector_type(8)));
typedef float f32x4 __attribute__((ext_vector_type(4)));

// async global->LDS, 16B per lane; lds base must be wave-uniform (m104/m108)
__device__ inline void async_cp16(bf16* lds, const bf16* g) {
    __builtin_amdgcn_global_load_lds(
        (const __attribute__((address_space(1))) unsigned int*)g,
        (__attribute__((address_space(3))) unsigned int*)lds, 16, 0, 0);
}

// ---------------- CSR build ----------------
__global__ void hist_kernel(const int* __restrict__ edst, int* counts) {
    int e = blockIdx.x * 256 + threadIdx.x;
    if (e >= E_TOT) return;
    int d = (e < NE) ? edst[e] : (e - NE);
    atomicAdd(&counts[d], 1);
}

__global__ void scan_kernel(const int* __restrict__ counts,
                            int* __restrict__ row_start, int* __restrict__ cursor) {
    __shared__ int part[256];
    __shared__ int pre[257];
    int t = threadIdx.x;
    int base = t * 16;
    int local[16];
    int s = 0;
#pragma unroll
    for (int i = 0; i < 16; ++i) { local[i] = s; s += counts[base + i]; }
    part[t] = s;
    __syncthreads();
    if (t == 0) {
        int r = 0;
        for (int i = 0; i < 256; ++i) { pre[i] = r; r += part[i]; }
        pre[256] = r;
    }
    __syncthreads();
    int off = pre[t];
#pragma unroll
    for (int i = 0; i < 16; ++i) {
        int v = off + local[i];
        row_start[base + i] = v;
        cursor[base + i] = v;
    }
    if (t == 0) row_start[N_NODES] = pre[256];
}

__global__ void scatter_kernel(const int* __restrict__ edst,
                               int* cursor, int* __restrict__ elist) {
    int e = blockIdx.x * 256 + threadIdx.x;
    if (e >= E_TOT) return;
    int d = (e < NE) ? edst[e] : (e - NE);
    int slot = atomicAdd(&cursor[d], 1);
    elist[slot] = e;
}

// ------------- merged operand prep: tobf16(x) | W1^T | W2^T | att-fold ------
// block ranges: [0,512) x->bf16 ; [512,1536) W1 transpose ; [1536,4096) W2
// transpose ; [4096,4160) fold att1 into W1 (w1s/w1d).
#define PB_X   512
#define PB_W1  1024
#define PB_W2  2560
__global__ __launch_bounds__(256)
void prep_kernel(const float* __restrict__ x, bf16* __restrict__ xb,
                 const float* __restrict__ W1, bf16* __restrict__ W1T,
                 const float* __restrict__ W2, bf16* __restrict__ W2T,
                 const float* __restrict__ as1, const float* __restrict__ ad1,
                 bf16* __restrict__ w1s, bf16* __restrict__ w1d) {
    __shared__ float tile[32][33];
    int b = blockIdx.x, t = threadIdx.x;
    if (b < PB_X) {
        int i = b * 256 + t;
        f32x4 a = *(const f32x4*)(x + (size_t)i * 8);
        f32x4 c = *(const f32x4*)(x + (size_t)i * 8 + 4);
        bf16x8 r;
        r[0] = (bf16)a[0]; r[1] = (bf16)a[1]; r[2] = (bf16)a[2]; r[3] = (bf16)a[3];
        r[4] = (bf16)c[0]; r[5] = (bf16)c[1]; r[6] = (bf16)c[2]; r[7] = (bf16)c[3];
        *(bf16x8*)(xb + (size_t)i * 8) = r;
    } else if (b < PB_X + PB_W1 + PB_W2) {
        const float* S; bf16* D; int R, C, gx, gy;
        if (b < PB_X + PB_W1) {
            int bb = b - PB_X;                    // W1: 256 x 4096
            S = W1; D = W1T; R = IN_FEAT; C = F1;
            gx = bb % (F1 / 32); gy = bb / (F1 / 32);
        } else {
            int bb = b - PB_X - PB_W1;            // W2: 4096 x 640
            S = W2; D = W2T; R = F1; C = F2;
            gx = bb % (F2 / 32); gy = bb / (F2 / 32);
        }
        int tx = t & 31, ty = t >> 5;
        int c0 = gx * 32, r0 = gy * 32;
#pragma unroll
        for (int i = 0; i < 4; ++i)
            tile[ty + i * 8][tx] = S[(size_t)(r0 + ty + i * 8) * C + c0 + tx];
        __syncthreads();
#pragma unroll
        for (int i = 0; i < 4; ++i)
            D[(size_t)(c0 + ty + i * 8) * R + r0 + tx] = (bf16)tile[tx][ty + i * 8];
    } else {
        int id = (b - PB_X - PB_W1 - PB_W2) * 256 + t;  // 16384 = 256k x 64h
        int k = id >> 6, h = id & 63;
        const float* wrow = W1 + (size_t)k * F1 + h * HID;
        const float* a1 = as1 + h * HID;
        const float* a2 = ad1 + h * HID;
        float s = 0.f, d = 0.f;
#pragma unroll 8
        for (int c = 0; c < HID; ++c) {
            float w = wrow[c];
            s += w * a1[c];
            d += w * a2[c];
        }
        w1s[id] = (bf16)s;
        w1d[id] = (bf16)d;
    }
}

// ---------------- MFMA GEMM: C[M,N] = A[M,K] @ BT[N,K]^T ----------------
// BM=BN=128, BK=64; 4 waves in 2x2, each wave a 64x64 tile (4x4 frags of
// 16x16x32). XOR-swizzled LDS (16B chunk c of row r stored at c^(r&7)):
// staging lane permutes its GLOBAL column (same 128B line, coalescing and
// global_load_lds lane mapping intact); frag reader applies same xor ->
// 2-way bank spread (free, m136). Round-4 verified: 0 bank conflicts.
// SWZ grouping (GEMM2 only, grid=640): assume XCD = bid%8 round-robin; the
// 5 n-blocks sharing an A-tile are placed consecutively on one XCD so the
// A-tile is fetched into that L2 once, reused 5x. Correctness-neutral.
template <int SPLITK, bool ATOMIC, bool SWZ, typename TC>
__global__ __launch_bounds__(256)
void gemm128_kernel(const bf16* __restrict__ A, const bf16* __restrict__ BT,
                    TC* __restrict__ C, int M, int N, int K) {
    __shared__ bf16 As[128][64];
    __shared__ bf16 Bs[128][64];
    const int tid  = threadIdx.x;
    const int wave = tid >> 6, lane = tid & 63;
    const int quad = lane >> 4, lr = lane & 15;
    int nb, mb, zb;
    if constexpr (SWZ) {
        // 640 blocks: x=bid&7 (XCD), q=bid>>3; group g=(q/5)*8+x in [0,128);
        // n=q%5; m=g>>2; z=g&3
        int bid = blockIdx.x;
        int xx = bid & 7, q = bid >> 3;
        int gp = q / 5; nb = q - gp * 5;
        int g = gp * 8 + xx;
        mb = g >> 2; zb = g & 3;
    } else {
        nb = blockIdx.x; mb = blockIdx.y; zb = blockIdx.z;
    }
    const int m0 = mb * 128, n0 = nb * 128;
    const int kchunk = K / SPLITK;
    const int kbeg = zb * kchunk;
    const int wm = (wave >> 1) * 64;
    const int wn = (wave & 1) * 64;

    const int srow = lane >> 3;                 // 0..7 row offset in 8-row chunk
    const int scol = ((lane & 7) ^ srow) * 8;   // swizzled global column (elems)
    const int xk = lr & 7;                      // frag-read xor key

    f32x4 acc[4][4] = {};

    for (int kk = 0; kk < kchunk; kk += 64) {
        int k0 = kbeg + kk;
#pragma unroll
        for (int c = 0; c < 4; ++c) {
            int r = wave * 32 + c * 8;
            async_cp16(&As[r][0], A + (size_t)(m0 + r + srow) * K + k0 + scol);
            async_cp16(&Bs[r][0], BT + (size_t)(n0 + r + srow) * K + k0 + scol);
        }
        __syncthreads();   // drains vmcnt before LDS reads

#pragma unroll
        for (int ks = 0; ks < 2; ++ks) {
            int ch = ((ks * 4 + quad) ^ xk) * 8;
            bf16x8 af[4], bfr[4];
#pragma unroll
            for (int mt = 0; mt < 4; ++mt)
                af[mt] = *(const bf16x8*)(&As[wm + mt * 16 + lr][ch]);
#pragma unroll
            for (int nt = 0; nt < 4; ++nt)
                bfr[nt] = *(const bf16x8*)(&Bs[wn + nt * 16 + lr][ch]);
#pragma unroll
            for (int mt = 0; mt < 4; ++mt)
#pragma unroll
                for (int nt = 0; nt < 4; ++nt)
                    acc[mt][nt] = __builtin_amdgcn_mfma_f32_16x16x32_bf16(
                        af[mt], bfr[nt], acc[mt][nt], 0, 0, 0);
        }
        __syncthreads();
    }

#pragma unroll
    for (int mt = 0; mt < 4; ++mt)
#pragma unroll
        for (int nt = 0; nt < 4; ++nt) {
            int row0 = m0 + wm + mt * 16 + quad * 4;
            int col = n0 + wn + nt * 16 + lr;
#pragma unroll
            for (int r = 0; r < 4; ++r) {
                if constexpr (ATOMIC)
                    atomicAdd((float*)&C[(size_t)(row0 + r) * N + col], acc[mt][nt][r]);
                else
                    C[(size_t)(row0 + r) * N + col] = (TC)acc[mt][nt][r];
            }
        }
}

// a_src1[n][h] = x[n,:] @ w1s[:,h]  — wave per node, lane = head
__global__ __launch_bounds__(256)
void gemv1_kernel(const float* __restrict__ x,
                  const bf16* __restrict__ w1s, const bf16* __restrict__ w1d,
                  float* __restrict__ a_src, float* __restrict__ a_dst) {
    int wave = threadIdx.x >> 6, lane = threadIdx.x & 63;
    int n = blockIdx.x * 4 + wave;
    const float* xr = x + (size_t)n * IN_FEAT;
    float s = 0.f, d = 0.f;
    for (int k0 = 0; k0 < IN_FEAT; k0 += 4) {
        f32x4 xv = *(const f32x4*)(xr + k0);   // wave-uniform -> broadcast
#pragma unroll
        for (int j = 0; j < 4; ++j) {
            float xs = xv[j];
            s += xs * (float)w1s[(k0 + j) * IN_HEAD + lane];
            d += xs * (float)w1d[(k0 + j) * IN_HEAD + lane];
        }
    }
    a_src[n * IN_HEAD + lane] = s;
    a_dst[n * IN_HEAD + lane] = d;
}

// ---------------- layer-2 attention dots ----------------
__global__ void att2_kernel(const float* __restrict__ H2,
                            const float* __restrict__ as2, const float* __restrict__ ad2,
                            float* __restrict__ a_src, float* __restrict__ a_dst) {
    int n = blockIdx.x, h = blockIdx.y, lane = threadIdx.x;
    const float* row = H2 + (size_t)n * F2 + h * OUT_FEAT;
    float v0 = row[lane], v1 = row[lane + 64];
    float s = v0 * as2[h * OUT_FEAT + lane] + v1 * as2[h * OUT_FEAT + lane + 64];
    float d = v0 * ad2[h * OUT_FEAT + lane] + v1 * ad2[h * OUT_FEAT + lane + 64];
#pragma unroll
    for (int off = 32; off > 0; off >>= 1) {
        s += __shfl_down(s, off);
        d += __shfl_down(d, off);
    }
    if (lane == 0) {
        a_src[n * OUT_HEAD + h] = s;
        a_dst[n * OUT_HEAD + h] = d;
    }
}

// ------- layer-1 aggregation: in-block softmax stats + gather, fused ELU ----
__global__ __launch_bounds__(256)
void agg1_kernel(const int* __restrict__ es, const int* __restrict__ row_start,
                 const int* __restrict__ elist,
                 const float* __restrict__ a_src, const float* __restrict__ a_dst,
                 const bf16* __restrict__ H1, const float* __restrict__ b1,
                 bf16* __restrict__ h_elu) {
    __shared__ int src_s[256];
    int d = blockIdx.x, t = threadIdx.x;
    int beg = row_start[d], end = row_start[d + 1], deg = end - beg;

    // online softmax stats: 4 threads per head, shuffle-merged
    int h = t >> 2, sub = t & 3;
    float adst = a_dst[d * IN_HEAD + h];
    float m = -1e30f, den = 0.f;
    for (int i = sub; i < deg; i += 4) {
        int e = elist[beg + i];
        int s = (e < NE) ? es[e] : d;
        float l = a_src[s * IN_HEAD + h] + adst;
        l = l > 0.f ? l : NEG_SLOPE * l;
        if (l > m) { den = den * __expf(m - l) + 1.f; m = l; }
        else den += __expf(l - m);
    }
#pragma unroll
    for (int o = 1; o <= 2; o <<= 1) {
        float mo = __shfl_xor(m, o);
        float dno = __shfl_xor(den, o);
        float mn = fmaxf(m, mo);
        den = den * __expf(m - mn) + dno * __expf(mo - mn);
        m = mn;
    }
    float dinv = 1.f / (den + EPS_A);

    // thread t owns 16 contiguous elems [t*16, t*16+16) -> head t>>2 == h
    float acc[16];
#pragma unroll
    for (int i = 0; i < 16; ++i) acc[i] = 0.f;

    for (int c0 = 0; c0 < deg; c0 += 256) {
        int cn = min(deg - c0, 256);
        __syncthreads();
        if (t < cn) {
            int e = elist[beg + c0 + t];
            src_s[t] = (e < NE) ? es[e] : d;
        }
        __syncthreads();
        for (int i = 0; i < cn; ++i) {
            int s = src_s[i];
            float l = a_src[s * IN_HEAD + h] + adst;
            l = l > 0.f ? l : NEG_SLOPE * l;
            float alpha = __expf(l - m) * dinv;
            const bf16* Hrow = H1 + (size_t)s * F1 + t * 16;
            bf16x8 v0 = *(const bf16x8*)Hrow;
            bf16x8 v1 = *(const bf16x8*)(Hrow + 8);
#pragma unroll
            for (int j = 0; j < 8; ++j) {
                acc[j]     += alpha * (float)v0[j];
                acc[8 + j] += alpha * (float)v1[j];
            }
        }
    }
#pragma unroll
    for (int j = 0; j < 16; ++j) {
        float v = acc[j] + b1[t * 16 + j];
        acc[j] = v > 0.f ? v : (__expf(v) - 1.f);   // ELU
    }
    bf16x8 o0, o1;
#pragma unroll
    for (int j = 0; j < 8; ++j) { o0[j] = (bf16)acc[j]; o1[j] = (bf16)acc[8 + j]; }
    *(bf16x8*)(h_elu + (size_t)d * F1 + t * 16) = o0;
    *(bf16x8*)(h_elu + (size_t)d * F1 + t * 16 + 8) = o1;
}

// --- layer-2 aggregation: stats + gather + head-mean + b2 + node-mean acc ---
__global__ __launch_bounds__(256)
void agg2_kernel(const int* __restrict__ es, const int* __restrict__ row_start,
                 const int* __restrict__ elist,
                 const float* __restrict__ a_src, const float* __restrict__ a_dst,
                 const float* __restrict__ H2, const float* __restrict__ b2,
                 float* __restrict__ acc_out) {
    __shared__ float m_s[OUT_HEAD], dinv_s[OUT_HEAD];
    __shared__ int src_s[256];
    __shared__ float buf[F2];
    int d = blockIdx.x, t = threadIdx.x;
    int beg = row_start[d], end = row_start[d + 1], deg = end - beg;

    // stats: 8 threads per head (t<40, wave 0), shuffle-merged
    if (t < 40) {
        int hh = t >> 3, sub = t & 7;
        float adst = a_dst[d * OUT_HEAD + hh];
        float m = -1e30f, den = 0.f;
        for (int i = sub; i < deg; i += 8) {
            int e = elist[beg + i];
            int s = (e < NE) ? es[e] : d;
            float l = a_src[s * OUT_HEAD + hh] + adst;
            l = l > 0.f ? l : NEG_SLOPE * l;
            if (l > m) { den = den * __expf(m - l) + 1.f; m = l; }
            else den += __expf(l - m);
        }
#pragma unroll
        for (int o = 1; o <= 4; o <<= 1) {
            float mo = __shfl_xor(m, o);
            float dno = __shfl_xor(den, o);
            float mn = fmaxf(m, mo);
            den = den * __expf(m - mn) + dno * __expf(mo - mn);
            m = mn;
        }
        if (sub == 0) { m_s[hh] = m; dinv_s[hh] = 1.f / (den + EPS_A); }
    }
    __syncthreads();

    // threads 0..159 own 4 contiguous fp32 at j=t*4; head = t>>5
    int h = t >> 5;
    float adst = 0.f, m = 0.f, dinv = 0.f;
    if (t < 160) {
        adst = a_dst[d * OUT_HEAD + h];
        m = m_s[h]; dinv = dinv_s[h];
    }
    float a0 = 0.f, a1 = 0.f, a2 = 0.f, a3 = 0.f;

    for (int c0 = 0; c0 < deg; c0 += 256) {
        int cn = min(deg - c0, 256);
        __syncthreads();
        if (t < cn) {
            int e = elist[beg + c0 + t];
            src_s[t] = (e < NE) ? es[e] : d;
        }
        __syncthreads();
        if (t < 160) {
            for (int i = 0; i < cn; ++i) {
                int s = src_s[i];
                float l = a_src[s * OUT_HEAD + h] + adst;
                l = l > 0.f ? l : NEG_SLOPE * l;
                float alpha = __expf(l - m) * dinv;
                f32x4 v = *(const f32x4*)(H2 + (size_t)s * F2 + t * 4);
                a0 += alpha * v[0]; a1 += alpha * v[1];
                a2 += alpha * v[2]; a3 += alpha * v[3];
            }
        }
    }
    if (t < 160) {
        buf[t * 4 + 0] = a0; buf[t * 4 + 1] = a1;
        buf[t * 4 + 2] = a2; buf[t * 4 + 3] = a3;
    }
    __syncthreads();
    if (t < OUT_FEAT) {
        float s = 0.f;
#pragma unroll
        for (int hh = 0; hh < OUT_HEAD; ++hh) s += buf[hh * OUT_FEAT + t];
        atomicAdd(&acc_out[t], s * (1.f / OUT_HEAD) + b2[t]);
    }
}

// ---------------- final tanh over node-mean accumulator ----------------
__global__ void tanh_kernel(const float* __restrict__ acc_out, float* __restrict__ out) {
    int c = threadIdx.x;
    out[c] = tanhf(acc_out[c] * (1.f / N_NODES));
}

// ---------------- launch ----------------
extern "C" void kernel_launch(void* const* d_in, const int* in_sizes, int n_in,
                              void* d_out, int out_size, void* d_ws, size_t ws_size,
                              hipStream_t stream) {
    const float* x        = (const float*)d_in[0];
    const int*   ei       = (const int*)d_in[1];
    const float* W1       = (const float*)d_in[2];
    const float* att_src1 = (const float*)d_in[3];
    const float* att_dst1 = (const float*)d_in[4];
    const float* b1       = (const float*)d_in[5];
    const float* W2       = (const float*)d_in[6];
    const float* att_src2 = (const float*)d_in[7];
    const float* att_dst2 = (const float*)d_in[8];
    const float* b2       = (const float*)d_in[9];
    float* out = (float*)d_out;

    const int* esrc = ei;
    const int* edst = ei + NE;

    // workspace carve (~86 MB)
    char* p = (char*)d_ws;
    auto bump = [&](size_t bytes) {
        void* r = (void*)p;
        p += (bytes + 255) & ~(size_t)255;
        return r;
    };
    bf16*  H1     = (bf16*)bump((size_t)N_NODES * F1 * 2);        // 32 MB
    bf16*  h_elu  = (bf16*)bump((size_t)N_NODES * F1 * 2);        // 32 MB
    float* H2     = (float*)bump((size_t)N_NODES * F2 * 4);       // 10.5 MB
    bf16*  xb     = (bf16*)bump((size_t)N_NODES * IN_FEAT * 2);   // 2 MB
    bf16*  W1T    = (bf16*)bump((size_t)F1 * IN_FEAT * 2);        // 2 MB
    bf16*  W2T    = (bf16*)bump((size_t)F2 * F1 * 2);             // 5 MB
    bf16*  w1s    = (bf16*)bump((size_t)IN_FEAT * IN_HEAD * 2);
    bf16*  w1d    = (bf16*)bump((size_t)IN_FEAT * IN_HEAD * 2);
    float* a_src1 = (float*)bump((size_t)N_NODES * IN_HEAD * 4);
    float* a_dst1 = (float*)bump((size_t)N_NODES * IN_HEAD * 4);
    float* a_src2 = (float*)bump((size_t)N_NODES * OUT_HEAD * 4);
    float* a_dst2 = (float*)bump((size_t)N_NODES * OUT_HEAD * 4);
    int*   counts = (int*)bump(N_NODES * 4 + 512);   // + acc_out (contiguous memset)
    float* acc_out = (float*)((char*)counts + N_NODES * 4);
    int*   row_start = (int*)bump((N_NODES + 1) * 4);
    int*   cursor = (int*)bump(N_NODES * 4);
    int*   elist  = (int*)bump(E_TOT * 4);

    // zero-init (capture-safe async memsets)
    hipMemsetAsync(counts, 0, N_NODES * 4 + 512, stream);
    hipMemsetAsync(H2, 0, (size_t)N_NODES * F2 * 4, stream);

    // CSR
    hist_kernel<<<(E_TOT + 255) / 256, 256, 0, stream>>>(edst, counts);
    scan_kernel<<<1, 256, 0, stream>>>(counts, row_start, cursor);
    scatter_kernel<<<(E_TOT + 255) / 256, 256, 0, stream>>>(edst, cursor, elist);

    // operand prep (merged)
    prep_kernel<<<PB_X + PB_W1 + PB_W2 + 64, 256, 0, stream>>>(
        x, xb, W1, W1T, W2, W2T, att_src1, att_dst1, w1s, w1d);

    // layer 1
    gemm128_kernel<1, false, false, bf16>
        <<<dim3(F1 / 128, N_NODES / 128, 1), 256, 0, stream>>>(
        xb, W1T, H1, N_NODES, F1, IN_FEAT);
    gemv1_kernel<<<N_NODES / 4, 256, 0, stream>>>(x, w1s, w1d, a_src1, a_dst1);
    agg1_kernel<<<N_NODES, 256, 0, stream>>>(
        esrc, row_start, elist, a_src1, a_dst1, H1, b1, h_elu);

    // layer 2: grid 640 = 8 XCD-slots x 16 groups x 5 n-blocks (SWZ decode)
    gemm128_kernel<4, true, true, float><<<640, 256, 0, stream>>>(
        h_elu, W2T, H2, N_NODES, F2, F1);
    att2_kernel<<<dim3(N_NODES, OUT_HEAD), 64, 0, stream>>>(
        H2, att_src2, att_dst2, a_src2, a_dst2);
    agg2_kernel<<<N_NODES, 256, 0, stream>>>(
        esrc, row_start, elist, a_src2, a_dst2, H2, b2, acc_out);

    // final
    tanh_kernel<<<1, OUT_FEAT, 0, stream>>>(acc_out, out);
}

// Round 6
// 294.495 us; speedup vs baseline: 1.2739x; 1.2739x over previous
//
#include <hip/hip_runtime.h>
#include <hip/hip_bf16.h>

// ---------------- problem constants ----------------
#define N_NODES 4096
#define NE      32768           // raw edges
#define E_TOT   (NE + N_NODES)  // + self loops = 36864
#define IN_FEAT 256
#define HID     64
#define IN_HEAD 64
#define F1      4096            // IN_HEAD*HID
#define OUT_HEAD 5
#define OUT_FEAT 128
#define F2      640             // OUT_HEAD*OUT_FEAT
#define NEG_SLOPE 0.2f
#define EPS_A   1e-16f

typedef __bf16 bf16;
typedef bf16 bf16x8 __attribute__((ext_vector_type(8)));
typedef float f32x4 __attribute__((ext_vector_type(4)));

// async global->LDS, 16B per lane; lds base must be wave-uniform (m104/m108)
__device__ inline void async_cp16(bf16* lds, const bf16* g) {
    __builtin_amdgcn_global_load_lds(
        (const __attribute__((address_space(1))) unsigned int*)g,
        (__attribute__((address_space(3))) unsigned int*)lds, 16, 0, 0);
}

// ---------------- CSR build ----------------
__global__ void hist_kernel(const int* __restrict__ edst, int* counts) {
    int e = blockIdx.x * 256 + threadIdx.x;
    if (e >= E_TOT) return;
    int d = (e < NE) ? edst[e] : (e - NE);
    atomicAdd(&counts[d], 1);
}

__global__ void scan_kernel(const int* __restrict__ counts,
                            int* __restrict__ row_start, int* __restrict__ cursor) {
    __shared__ int part[256];
    __shared__ int pre[257];
    int t = threadIdx.x;
    int base = t * 16;
    int local[16];
    int s = 0;
#pragma unroll
    for (int i = 0; i < 16; ++i) { local[i] = s; s += counts[base + i]; }
    part[t] = s;
    __syncthreads();
    if (t == 0) {
        int r = 0;
        for (int i = 0; i < 256; ++i) { pre[i] = r; r += part[i]; }
        pre[256] = r;
    }
    __syncthreads();
    int off = pre[t];
#pragma unroll
    for (int i = 0; i < 16; ++i) {
        int v = off + local[i];
        row_start[base + i] = v;
        cursor[base + i] = v;
    }
    if (t == 0) row_start[N_NODES] = pre[256];
}

__global__ void scatter_kernel(const int* __restrict__ edst,
                               int* cursor, int* __restrict__ elist) {
    int e = blockIdx.x * 256 + threadIdx.x;
    if (e >= E_TOT) return;
    int d = (e < NE) ? edst[e] : (e - NE);
    int slot = atomicAdd(&cursor[d], 1);
    elist[slot] = e;
}

// ------------- merged operand prep: tobf16(x) | W1^T | W2^T | att-fold ------
#define PB_X   512
#define PB_W1  1024
#define PB_W2  2560
__global__ __launch_bounds__(256)
void prep_kernel(const float* __restrict__ x, bf16* __restrict__ xb,
                 const float* __restrict__ W1, bf16* __restrict__ W1T,
                 const float* __restrict__ W2, bf16* __restrict__ W2T,
                 const float* __restrict__ as1, const float* __restrict__ ad1,
                 bf16* __restrict__ w1s, bf16* __restrict__ w1d) {
    __shared__ float tile[32][33];
    int b = blockIdx.x, t = threadIdx.x;
    if (b < PB_X) {
        int i = b * 256 + t;
        f32x4 a = *(const f32x4*)(x + (size_t)i * 8);
        f32x4 c = *(const f32x4*)(x + (size_t)i * 8 + 4);
        bf16x8 r;
        r[0] = (bf16)a[0]; r[1] = (bf16)a[1]; r[2] = (bf16)a[2]; r[3] = (bf16)a[3];
        r[4] = (bf16)c[0]; r[5] = (bf16)c[1]; r[6] = (bf16)c[2]; r[7] = (bf16)c[3];
        *(bf16x8*)(xb + (size_t)i * 8) = r;
    } else if (b < PB_X + PB_W1 + PB_W2) {
        const float* S; bf16* D; int R, C, gx, gy;
        if (b < PB_X + PB_W1) {
            int bb = b - PB_X;                    // W1: 256 x 4096
            S = W1; D = W1T; R = IN_FEAT; C = F1;
            gx = bb % (F1 / 32); gy = bb / (F1 / 32);
        } else {
            int bb = b - PB_X - PB_W1;            // W2: 4096 x 640
            S = W2; D = W2T; R = F1; C = F2;
            gx = bb % (F2 / 32); gy = bb / (F2 / 32);
        }
        int tx = t & 31, ty = t >> 5;
        int c0 = gx * 32, r0 = gy * 32;
#pragma unroll
        for (int i = 0; i < 4; ++i)
            tile[ty + i * 8][tx] = S[(size_t)(r0 + ty + i * 8) * C + c0 + tx];
        __syncthreads();
#pragma unroll
        for (int i = 0; i < 4; ++i)
            D[(size_t)(c0 + ty + i * 8) * R + r0 + tx] = (bf16)tile[tx][ty + i * 8];
    } else {
        int id = (b - PB_X - PB_W1 - PB_W2) * 256 + t;  // 16384 = 256k x 64h
        int k = id >> 6, h = id & 63;
        const float* wrow = W1 + (size_t)k * F1 + h * HID;
        const float* a1 = as1 + h * HID;
        const float* a2 = ad1 + h * HID;
        float s = 0.f, d = 0.f;
#pragma unroll 8
        for (int c = 0; c < HID; ++c) {
            float w = wrow[c];
            s += w * a1[c];
            d += w * a2[c];
        }
        w1s[id] = (bf16)s;
        w1d[id] = (bf16)d;
    }
}

// ---------------- MFMA GEMM: C[M,N] = A[M,K] @ BT[N,K]^T ----------------
// BM=BN=128, BK=64; XOR-swizzled LDS (0 bank conflicts, verified r4).
// SWZ: XCD-grouped 1D grid for GEMM2 (see r5 comments).
template <int SPLITK, bool ATOMIC, bool SWZ, typename TC>
__global__ __launch_bounds__(256)
void gemm128_kernel(const bf16* __restrict__ A, const bf16* __restrict__ BT,
                    TC* __restrict__ C, int M, int N, int K) {
    __shared__ bf16 As[128][64];
    __shared__ bf16 Bs[128][64];
    const int tid  = threadIdx.x;
    const int wave = tid >> 6, lane = tid & 63;
    const int quad = lane >> 4, lr = lane & 15;
    int nb, mb, zb;
    if constexpr (SWZ) {
        int bid = blockIdx.x;
        int xx = bid & 7, q = bid >> 3;
        int gp = q / 5; nb = q - gp * 5;
        int g = gp * 8 + xx;
        mb = g >> 2; zb = g & 3;
    } else {
        nb = blockIdx.x; mb = blockIdx.y; zb = blockIdx.z;
    }
    const int m0 = mb * 128, n0 = nb * 128;
    const int kchunk = K / SPLITK;
    const int kbeg = zb * kchunk;
    const int wm = (wave >> 1) * 64;
    const int wn = (wave & 1) * 64;

    const int srow = lane >> 3;
    const int scol = ((lane & 7) ^ srow) * 8;
    const int xk = lr & 7;

    f32x4 acc[4][4] = {};

    for (int kk = 0; kk < kchunk; kk += 64) {
        int k0 = kbeg + kk;
#pragma unroll
        for (int c = 0; c < 4; ++c) {
            int r = wave * 32 + c * 8;
            async_cp16(&As[r][0], A + (size_t)(m0 + r + srow) * K + k0 + scol);
            async_cp16(&Bs[r][0], BT + (size_t)(n0 + r + srow) * K + k0 + scol);
        }
        __syncthreads();

#pragma unroll
        for (int ks = 0; ks < 2; ++ks) {
            int ch = ((ks * 4 + quad) ^ xk) * 8;
            bf16x8 af[4], bfr[4];
#pragma unroll
            for (int mt = 0; mt < 4; ++mt)
                af[mt] = *(const bf16x8*)(&As[wm + mt * 16 + lr][ch]);
#pragma unroll
            for (int nt = 0; nt < 4; ++nt)
                bfr[nt] = *(const bf16x8*)(&Bs[wn + nt * 16 + lr][ch]);
#pragma unroll
            for (int mt = 0; mt < 4; ++mt)
#pragma unroll
                for (int nt = 0; nt < 4; ++nt)
                    acc[mt][nt] = __builtin_amdgcn_mfma_f32_16x16x32_bf16(
                        af[mt], bfr[nt], acc[mt][nt], 0, 0, 0);
        }
        __syncthreads();
    }

#pragma unroll
    for (int mt = 0; mt < 4; ++mt)
#pragma unroll
        for (int nt = 0; nt < 4; ++nt) {
            int row0 = m0 + wm + mt * 16 + quad * 4;
            int col = n0 + wn + nt * 16 + lr;
#pragma unroll
            for (int r = 0; r < 4; ++r) {
                if constexpr (ATOMIC)
                    atomicAdd((float*)&C[(size_t)(row0 + r) * N + col], acc[mt][nt][r]);
                else
                    C[(size_t)(row0 + r) * N + col] = (TC)acc[mt][nt][r];
            }
        }
}

// a_src1[n][h] = x[n,:] @ w1s[:,h]  — wave per node, lane = head
__global__ __launch_bounds__(256)
void gemv1_kernel(const float* __restrict__ x,
                  const bf16* __restrict__ w1s, const bf16* __restrict__ w1d,
                  float* __restrict__ a_src, float* __restrict__ a_dst) {
    int wave = threadIdx.x >> 6, lane = threadIdx.x & 63;
    int n = blockIdx.x * 4 + wave;
    const float* xr = x + (size_t)n * IN_FEAT;
    float s = 0.f, d = 0.f;
    for (int k0 = 0; k0 < IN_FEAT; k0 += 4) {
        f32x4 xv = *(const f32x4*)(xr + k0);
#pragma unroll
        for (int j = 0; j < 4; ++j) {
            float xs = xv[j];
            s += xs * (float)w1s[(k0 + j) * IN_HEAD + lane];
            d += xs * (float)w1d[(k0 + j) * IN_HEAD + lane];
        }
    }
    a_src[n * IN_HEAD + lane] = s;
    a_dst[n * IN_HEAD + lane] = d;
}

// ---------------- layer-2 attention dots ----------------
__global__ void att2_kernel(const float* __restrict__ H2,
                            const float* __restrict__ as2, const float* __restrict__ ad2,
                            float* __restrict__ a_src, float* __restrict__ a_dst) {
    int n = blockIdx.x, h = blockIdx.y, lane = threadIdx.x;
    const float* row = H2 + (size_t)n * F2 + h * OUT_FEAT;
    float v0 = row[lane], v1 = row[lane + 64];
    float s = v0 * as2[h * OUT_FEAT + lane] + v1 * as2[h * OUT_FEAT + lane + 64];
    float d = v0 * ad2[h * OUT_FEAT + lane] + v1 * ad2[h * OUT_FEAT + lane + 64];
#pragma unroll
    for (int off = 32; off > 0; off >>= 1) {
        s += __shfl_down(s, off);
        d += __shfl_down(d, off);
    }
    if (lane == 0) {
        a_src[n * OUT_HEAD + h] = s;
        a_dst[n * OUT_HEAD + h] = d;
    }
}

// ------- layer-1 aggregation: in-block softmax stats + gather, fused ELU ----
__global__ __launch_bounds__(256)
void agg1_kernel(const int* __restrict__ es, const int* __restrict__ row_start,
                 const int* __restrict__ elist,
                 const float* __restrict__ a_src, const float* __restrict__ a_dst,
                 const bf16* __restrict__ H1, const float* __restrict__ b1,
                 bf16* __restrict__ h_elu) {
    __shared__ int src_s[256];
    int d = blockIdx.x, t = threadIdx.x;
    int beg = row_start[d], end = row_start[d + 1], deg = end - beg;

    // online softmax stats: 4 threads per head, shuffle-merged
    int h = t >> 2, sub = t & 3;
    float adst = a_dst[d * IN_HEAD + h];
    float m = -1e30f, den = 0.f;
    for (int i = sub; i < deg; i += 4) {
        int e = elist[beg + i];
        int s = (e < NE) ? es[e] : d;
        float l = a_src[s * IN_HEAD + h] + adst;
        l = l > 0.f ? l : NEG_SLOPE * l;
        if (l > m) { den = den * __expf(m - l) + 1.f; m = l; }
        else den += __expf(l - m);
    }
#pragma unroll
    for (int o = 1; o <= 2; o <<= 1) {
        float mo = __shfl_xor(m, o);
        float dno = __shfl_xor(den, o);
        float mn = fmaxf(m, mo);
        den = den * __expf(m - mn) + dno * __expf(mo - mn);
        m = mn;
    }
    float dinv = 1.f / (den + EPS_A);

    float acc[16];
#pragma unroll
    for (int i = 0; i < 16; ++i) acc[i] = 0.f;

    for (int c0 = 0; c0 < deg; c0 += 256) {
        int cn = min(deg - c0, 256);
        __syncthreads();
        if (t < cn) {
            int e = elist[beg + c0 + t];
            src_s[t] = (e < NE) ? es[e] : d;
        }
        __syncthreads();
        for (int i = 0; i < cn; ++i) {
            int s = src_s[i];
            float l = a_src[s * IN_HEAD + h] + adst;
            l = l > 0.f ? l : NEG_SLOPE * l;
            float alpha = __expf(l - m) * dinv;
            const bf16* Hrow = H1 + (size_t)s * F1 + t * 16;
            bf16x8 v0 = *(const bf16x8*)Hrow;
            bf16x8 v1 = *(const bf16x8*)(Hrow + 8);
#pragma unroll
            for (int j = 0; j < 8; ++j) {
                acc[j]     += alpha * (float)v0[j];
                acc[8 + j] += alpha * (float)v1[j];
            }
        }
    }
#pragma unroll
    for (int j = 0; j < 16; ++j) {
        float v = acc[j] + b1[t * 16 + j];
        acc[j] = v > 0.f ? v : (__expf(v) - 1.f);   // ELU
    }
    bf16x8 o0, o1;
#pragma unroll
    for (int j = 0; j < 8; ++j) { o0[j] = (bf16)acc[j]; o1[j] = (bf16)acc[8 + j]; }
    *(bf16x8*)(h_elu + (size_t)d * F1 + t * 16) = o0;
    *(bf16x8*)(h_elu + (size_t)d * F1 + t * 16 + 8) = o1;
}

// ------- layer-2 softmax stats: thread per (dst,head) over CSR ----------
__global__ void stats2_kernel(const int* __restrict__ es,
                              const int* __restrict__ row_start,
                              const int* __restrict__ elist,
                              const float* __restrict__ a_src,
                              const float* __restrict__ a_dst,
                              float* __restrict__ m2, float* __restrict__ dinv2) {
    int id = blockIdx.x * 256 + threadIdx.x;
    if (id >= N_NODES * OUT_HEAD) return;
    int d = id / OUT_HEAD, h = id - d * OUT_HEAD;
    int beg = row_start[d], deg = row_start[d + 1] - beg;
    float adst = a_dst[id];
    float m = -1e30f, den = 0.f;
    for (int i = 0; i < deg; ++i) {
        int e = elist[beg + i];
        int s = (e < NE) ? es[e] : d;
        float l = a_src[s * OUT_HEAD + h] + adst;
        l = l > 0.f ? l : NEG_SLOPE * l;
        if (l > m) { den = den * __expf(m - l) + 1.f; m = l; }
        else den += __expf(l - m);
    }
    m2[id] = m;
    dinv2[id] = 1.f / (den + EPS_A);
}

// ------- beta[s][h] = sum over edges with src s of alpha2[e][h] ----------
__global__ void beta_kernel(const int* __restrict__ es, const int* __restrict__ ed,
                            const float* __restrict__ a_src, const float* __restrict__ a_dst,
                            const float* __restrict__ m2, const float* __restrict__ dinv2,
                            float* __restrict__ beta) {
    int id = blockIdx.x * 256 + threadIdx.x;
    if (id >= E_TOT * OUT_HEAD) return;
    int e = id / OUT_HEAD, h = id - e * OUT_HEAD;
    int s = (e < NE) ? es[e] : (e - NE);
    int d = (e < NE) ? ed[e] : (e - NE);
    float l = a_src[s * OUT_HEAD + h] + a_dst[d * OUT_HEAD + h];
    l = l > 0.f ? l : NEG_SLOPE * l;
    float alpha = __expf(l - m2[d * OUT_HEAD + h]) * dinv2[d * OUT_HEAD + h];
    atomicAdd(&beta[s * OUT_HEAD + h], alpha);
}

// ------- weighted column-sum of H2: total[c] = sum_s sum_h beta[s,h]H2[s,h*128+c]
// 128 blocks x 32 nodes each; 8-way striped atomic accumulators.
__global__ __launch_bounds__(256)
void wsum_kernel(const float* __restrict__ H2, const float* __restrict__ beta,
                 float* __restrict__ acc_out) {
    __shared__ float buf[F2];
    int t = threadIdx.x;
    int n0 = blockIdx.x * 32;
    int h = t >> 5;                      // for t<160: head of the f32x4 at j=4t
    float a0 = 0.f, a1 = 0.f, a2 = 0.f, a3 = 0.f;
    if (t < 160) {
        for (int i = 0; i < 32; ++i) {
            int s = n0 + i;
            float bh = beta[s * OUT_HEAD + h];
            f32x4 v = *(const f32x4*)(H2 + (size_t)s * F2 + t * 4);
            a0 += bh * v[0]; a1 += bh * v[1];
            a2 += bh * v[2]; a3 += bh * v[3];
        }
        buf[t * 4 + 0] = a0; buf[t * 4 + 1] = a1;
        buf[t * 4 + 2] = a2; buf[t * 4 + 3] = a3;
    }
    __syncthreads();
    if (t < OUT_FEAT) {
        float s = 0.f;
#pragma unroll
        for (int hh = 0; hh < OUT_HEAD; ++hh) s += buf[hh * OUT_FEAT + t];
        atomicAdd(&acc_out[(blockIdx.x & 7) * OUT_FEAT + t], s);
    }
}

// ---------------- final: fold stripes, scale, +b2, tanh ----------------
__global__ void tanh_kernel(const float* __restrict__ acc_out,
                            const float* __restrict__ b2, float* __restrict__ out) {
    int c = threadIdx.x;
    float tot = 0.f;
#pragma unroll
    for (int k = 0; k < 8; ++k) tot += acc_out[k * OUT_FEAT + c];
    out[c] = tanhf(tot * (1.f / (OUT_HEAD * (float)N_NODES)) + b2[c]);
}

// ---------------- launch ----------------
extern "C" void kernel_launch(void* const* d_in, const int* in_sizes, int n_in,
                              void* d_out, int out_size, void* d_ws, size_t ws_size,
                              hipStream_t stream) {
    const float* x        = (const float*)d_in[0];
    const int*   ei       = (const int*)d_in[1];
    const float* W1       = (const float*)d_in[2];
    const float* att_src1 = (const float*)d_in[3];
    const float* att_dst1 = (const float*)d_in[4];
    const float* b1       = (const float*)d_in[5];
    const float* W2       = (const float*)d_in[6];
    const float* att_src2 = (const float*)d_in[7];
    const float* att_dst2 = (const float*)d_in[8];
    const float* b2       = (const float*)d_in[9];
    float* out = (float*)d_out;

    const int* esrc = ei;
    const int* edst = ei + NE;

    // workspace carve (~86 MB)
    char* p = (char*)d_ws;
    auto bump = [&](size_t bytes) {
        void* r = (void*)p;
        p += (bytes + 255) & ~(size_t)255;
        return r;
    };
    bf16*  H1     = (bf16*)bump((size_t)N_NODES * F1 * 2);        // 32 MB
    bf16*  h_elu  = (bf16*)bump((size_t)N_NODES * F1 * 2);        // 32 MB
    float* H2     = (float*)bump((size_t)N_NODES * F2 * 4);       // 10.5 MB
    bf16*  xb     = (bf16*)bump((size_t)N_NODES * IN_FEAT * 2);   // 2 MB
    bf16*  W1T    = (bf16*)bump((size_t)F1 * IN_FEAT * 2);        // 2 MB
    bf16*  W2T    = (bf16*)bump((size_t)F2 * F1 * 2);             // 5 MB
    bf16*  w1s    = (bf16*)bump((size_t)IN_FEAT * IN_HEAD * 2);
    bf16*  w1d    = (bf16*)bump((size_t)IN_FEAT * IN_HEAD * 2);
    float* a_src1 = (float*)bump((size_t)N_NODES * IN_HEAD * 4);
    float* a_dst1 = (float*)bump((size_t)N_NODES * IN_HEAD * 4);
    float* a_src2 = (float*)bump((size_t)N_NODES * OUT_HEAD * 4);
    float* a_dst2 = (float*)bump((size_t)N_NODES * OUT_HEAD * 4);
    float* m2     = (float*)bump((size_t)N_NODES * OUT_HEAD * 4);
    float* dinv2  = (float*)bump((size_t)N_NODES * OUT_HEAD * 4);
    int*   row_start = (int*)bump((N_NODES + 1) * 4);
    int*   cursor = (int*)bump(N_NODES * 4);
    int*   elist  = (int*)bump(E_TOT * 4);
    // zeroed region: counts | beta | acc_out (one contiguous memset)
    int*   counts = (int*)bump(N_NODES * 4 + N_NODES * OUT_HEAD * 4 + 8 * OUT_FEAT * 4);
    float* beta    = (float*)((char*)counts + N_NODES * 4);
    float* acc_out = beta + N_NODES * OUT_HEAD;

    hipMemsetAsync(counts, 0,
                   N_NODES * 4 + N_NODES * OUT_HEAD * 4 + 8 * OUT_FEAT * 4, stream);
    hipMemsetAsync(H2, 0, (size_t)N_NODES * F2 * 4, stream);

    // CSR
    hist_kernel<<<(E_TOT + 255) / 256, 256, 0, stream>>>(edst, counts);
    scan_kernel<<<1, 256, 0, stream>>>(counts, row_start, cursor);
    scatter_kernel<<<(E_TOT + 255) / 256, 256, 0, stream>>>(edst, cursor, elist);

    // operand prep (merged)
    prep_kernel<<<PB_X + PB_W1 + PB_W2 + 64, 256, 0, stream>>>(
        x, xb, W1, W1T, W2, W2T, att_src1, att_dst1, w1s, w1d);

    // layer 1
    gemm128_kernel<1, false, false, bf16>
        <<<dim3(F1 / 128, N_NODES / 128, 1), 256, 0, stream>>>(
        xb, W1T, H1, N_NODES, F1, IN_FEAT);
    gemv1_kernel<<<N_NODES / 4, 256, 0, stream>>>(x, w1s, w1d, a_src1, a_dst1);
    agg1_kernel<<<N_NODES, 256, 0, stream>>>(
        esrc, row_start, elist, a_src1, a_dst1, H1, b1, h_elu);

    // layer 2
    gemm128_kernel<4, true, true, float><<<640, 256, 0, stream>>>(
        h_elu, W2T, H2, N_NODES, F2, F1);
    att2_kernel<<<dim3(N_NODES, OUT_HEAD), 64, 0, stream>>>(
        H2, att_src2, att_dst2, a_src2, a_dst2);
    stats2_kernel<<<(N_NODES * OUT_HEAD + 255) / 256, 256, 0, stream>>>(
        esrc, row_start, elist, a_src2, a_dst2, m2, dinv2);
    beta_kernel<<<(E_TOT * OUT_HEAD + 255) / 256, 256, 0, stream>>>(
        esrc, edst, a_src2, a_dst2, m2, dinv2, beta);
    wsum_kernel<<<N_NODES / 32, 256, 0, stream>>>(H2, beta, acc_out);

    // final
    tanh_kernel<<<1, OUT_FEAT, 0, stream>>>(acc_out, b2, out);
}

// Round 7
// 253.558 us; speedup vs baseline: 1.4795x; 1.1615x over previous
//
#include <hip/hip_runtime.h>
#include <hip/hip_bf16.h>

// ---------------- problem constants ----------------
#define N_NODES 4096
#define NE      32768           // raw edges
#define E_TOT   (NE + N_NODES)  // + self loops = 36864
#define IN_FEAT 256
#define HID     64
#define IN_HEAD 64
#define F1      4096            // IN_HEAD*HID
#define OUT_HEAD 5
#define OUT_FEAT 128
#define F2      640             // OUT_HEAD*OUT_FEAT
#define NEG_SLOPE 0.2f
#define EPS_A   1e-16f

typedef __bf16 bf16;
typedef bf16 bf16x8 __attribute__((ext_vector_type(8)));
typedef bf16 bf16x4 __attribute__((ext_vector_type(4)));
typedef float f32x4 __attribute__((ext_vector_type(4)));

// async global->LDS, 16B per lane; lds base must be wave-uniform (m104/m108)
__device__ inline void async_cp16(bf16* lds, const bf16* g) {
    __builtin_amdgcn_global_load_lds(
        (const __attribute__((address_space(1))) unsigned int*)g,
        (__attribute__((address_space(3))) unsigned int*)lds, 16, 0, 0);
}

// ---------------- CSR build ----------------
__global__ void hist_kernel(const int* __restrict__ edst, int* counts) {
    int e = blockIdx.x * 256 + threadIdx.x;
    if (e >= E_TOT) return;
    int d = (e < NE) ? edst[e] : (e - NE);
    atomicAdd(&counts[d], 1);
}

__global__ void scan_kernel(const int* __restrict__ counts,
                            int* __restrict__ row_start, int* __restrict__ cursor) {
    __shared__ int part[256];
    __shared__ int pre[257];
    int t = threadIdx.x;
    int base = t * 16;
    int local[16];
    int s = 0;
#pragma unroll
    for (int i = 0; i < 16; ++i) { local[i] = s; s += counts[base + i]; }
    part[t] = s;
    __syncthreads();
    if (t == 0) {
        int r = 0;
        for (int i = 0; i < 256; ++i) { pre[i] = r; r += part[i]; }
        pre[256] = r;
    }
    __syncthreads();
    int off = pre[t];
#pragma unroll
    for (int i = 0; i < 16; ++i) {
        int v = off + local[i];
        row_start[base + i] = v;
        cursor[base + i] = v;
    }
    if (t == 0) row_start[N_NODES] = pre[256];
}

__global__ void scatter_kernel(const int* __restrict__ edst,
                               int* cursor, int* __restrict__ elist) {
    int e = blockIdx.x * 256 + threadIdx.x;
    if (e >= E_TOT) return;
    int d = (e < NE) ? edst[e] : (e - NE);
    int slot = atomicAdd(&cursor[d], 1);
    elist[slot] = e;
}

// ------------- merged operand prep: tobf16(x) | W1^T | W2^T | att-fold ------
#define PB_X   512
#define PB_W1  1024
#define PB_W2  2560
__global__ __launch_bounds__(256)
void prep_kernel(const float* __restrict__ x, bf16* __restrict__ xb,
                 const float* __restrict__ W1, bf16* __restrict__ W1T,
                 const float* __restrict__ W2, bf16* __restrict__ W2T,
                 const float* __restrict__ as1, const float* __restrict__ ad1,
                 bf16* __restrict__ w1s, bf16* __restrict__ w1d) {
    __shared__ float tile[32][33];
    int b = blockIdx.x, t = threadIdx.x;
    if (b < PB_X) {
        int i = b * 256 + t;
        f32x4 a = *(const f32x4*)(x + (size_t)i * 8);
        f32x4 c = *(const f32x4*)(x + (size_t)i * 8 + 4);
        bf16x8 r;
        r[0] = (bf16)a[0]; r[1] = (bf16)a[1]; r[2] = (bf16)a[2]; r[3] = (bf16)a[3];
        r[4] = (bf16)c[0]; r[5] = (bf16)c[1]; r[6] = (bf16)c[2]; r[7] = (bf16)c[3];
        *(bf16x8*)(xb + (size_t)i * 8) = r;
    } else if (b < PB_X + PB_W1 + PB_W2) {
        const float* S; bf16* D; int R, C, gx, gy;
        if (b < PB_X + PB_W1) {
            int bb = b - PB_X;                    // W1: 256 x 4096
            S = W1; D = W1T; R = IN_FEAT; C = F1;
            gx = bb % (F1 / 32); gy = bb / (F1 / 32);
        } else {
            int bb = b - PB_X - PB_W1;            // W2: 4096 x 640
            S = W2; D = W2T; R = F1; C = F2;
            gx = bb % (F2 / 32); gy = bb / (F2 / 32);
        }
        int tx = t & 31, ty = t >> 5;
        int c0 = gx * 32, r0 = gy * 32;
#pragma unroll
        for (int i = 0; i < 4; ++i)
            tile[ty + i * 8][tx] = S[(size_t)(r0 + ty + i * 8) * C + c0 + tx];
        __syncthreads();
#pragma unroll
        for (int i = 0; i < 4; ++i)
            D[(size_t)(c0 + ty + i * 8) * R + r0 + tx] = (bf16)tile[tx][ty + i * 8];
    } else {
        int id = (b - PB_X - PB_W1 - PB_W2) * 256 + t;  // 16384 = 256k x 64h
        int k = id >> 6, h = id & 63;
        const float* wrow = W1 + (size_t)k * F1 + h * HID;
        const float* a1 = as1 + h * HID;
        const float* a2 = ad1 + h * HID;
        float s = 0.f, d = 0.f;
#pragma unroll 8
        for (int c = 0; c < HID; ++c) {
            float w = wrow[c];
            s += w * a1[c];
            d += w * a2[c];
        }
        w1s[id] = (bf16)s;
        w1d[id] = (bf16)d;
    }
}

// ---------------- MFMA GEMM: C[M,N] = A[M,K] @ BT[N,K]^T ----------------
// BM=BN=128, BK=64; XOR-swizzled LDS (0 bank conflicts, verified r4).
// SWZ: XCD-grouped 1D grid for GEMM2 (FETCH 147->24 MB, verified r6).
// SPLITK>1: z-partials go to separate C buffers (C + z*M*N), PLAIN stores —
// the r4-r6 atomic epilogue (10.5M fp32 atomicAdds) was the 68 us limiter.
template <int SPLITK, bool SWZ, typename TC>
__global__ __launch_bounds__(256)
void gemm128_kernel(const bf16* __restrict__ A, const bf16* __restrict__ BT,
                    TC* __restrict__ C, int M, int N, int K) {
    __shared__ bf16 As[128][64];
    __shared__ bf16 Bs[128][64];
    const int tid  = threadIdx.x;
    const int wave = tid >> 6, lane = tid & 63;
    const int quad = lane >> 4, lr = lane & 15;
    int nb, mb, zb;
    if constexpr (SWZ) {
        int bid = blockIdx.x;
        int xx = bid & 7, q = bid >> 3;
        int gp = q / 5; nb = q - gp * 5;
        int g = gp * 8 + xx;
        mb = g >> 2; zb = g & 3;
    } else {
        nb = blockIdx.x; mb = blockIdx.y; zb = blockIdx.z;
    }
    const int m0 = mb * 128, n0 = nb * 128;
    const int kchunk = K / SPLITK;
    const int kbeg = zb * kchunk;
    const int wm = (wave >> 1) * 64;
    const int wn = (wave & 1) * 64;
    TC* Cz = C + (size_t)zb * M * N;

    const int srow = lane >> 3;
    const int scol = ((lane & 7) ^ srow) * 8;
    const int xk = lr & 7;

    f32x4 acc[4][4] = {};

    for (int kk = 0; kk < kchunk; kk += 64) {
        int k0 = kbeg + kk;
#pragma unroll
        for (int c = 0; c < 4; ++c) {
            int r = wave * 32 + c * 8;
            async_cp16(&As[r][0], A + (size_t)(m0 + r + srow) * K + k0 + scol);
            async_cp16(&Bs[r][0], BT + (size_t)(n0 + r + srow) * K + k0 + scol);
        }
        __syncthreads();

#pragma unroll
        for (int ks = 0; ks < 2; ++ks) {
            int ch = ((ks * 4 + quad) ^ xk) * 8;
            bf16x8 af[4], bfr[4];
#pragma unroll
            for (int mt = 0; mt < 4; ++mt)
                af[mt] = *(const bf16x8*)(&As[wm + mt * 16 + lr][ch]);
#pragma unroll
            for (int nt = 0; nt < 4; ++nt)
                bfr[nt] = *(const bf16x8*)(&Bs[wn + nt * 16 + lr][ch]);
#pragma unroll
            for (int mt = 0; mt < 4; ++mt)
#pragma unroll
                for (int nt = 0; nt < 4; ++nt)
                    acc[mt][nt] = __builtin_amdgcn_mfma_f32_16x16x32_bf16(
                        af[mt], bfr[nt], acc[mt][nt], 0, 0, 0);
        }
        __syncthreads();
    }

#pragma unroll
    for (int mt = 0; mt < 4; ++mt)
#pragma unroll
        for (int nt = 0; nt < 4; ++nt) {
            int row0 = m0 + wm + mt * 16 + quad * 4;
            int col = n0 + wn + nt * 16 + lr;
#pragma unroll
            for (int r = 0; r < 4; ++r)
                Cz[(size_t)(row0 + r) * N + col] = (TC)acc[mt][nt][r];
        }
}

// a_src1[n][h] = x[n,:] @ w1s[:,h]  — wave per node, lane = head
__global__ __launch_bounds__(256)
void gemv1_kernel(const float* __restrict__ x,
                  const bf16* __restrict__ w1s, const bf16* __restrict__ w1d,
                  float* __restrict__ a_src, float* __restrict__ a_dst) {
    int wave = threadIdx.x >> 6, lane = threadIdx.x & 63;
    int n = blockIdx.x * 4 + wave;
    const float* xr = x + (size_t)n * IN_FEAT;
    float s = 0.f, d = 0.f;
    for (int k0 = 0; k0 < IN_FEAT; k0 += 4) {
        f32x4 xv = *(const f32x4*)(xr + k0);
#pragma unroll
        for (int j = 0; j < 4; ++j) {
            float xs = xv[j];
            s += xs * (float)w1s[(k0 + j) * IN_HEAD + lane];
            d += xs * (float)w1d[(k0 + j) * IN_HEAD + lane];
        }
    }
    a_src[n * IN_HEAD + lane] = s;
    a_dst[n * IN_HEAD + lane] = d;
}

// ------- layer-1 aggregation: in-block softmax stats + gather, fused ELU ----
__global__ __launch_bounds__(256)
void agg1_kernel(const int* __restrict__ es, const int* __restrict__ row_start,
                 const int* __restrict__ elist,
                 const float* __restrict__ a_src, const float* __restrict__ a_dst,
                 const bf16* __restrict__ H1, const float* __restrict__ b1,
                 bf16* __restrict__ h_elu) {
    __shared__ int src_s[256];
    int d = blockIdx.x, t = threadIdx.x;
    int beg = row_start[d], end = row_start[d + 1], deg = end - beg;

    // online softmax stats: 4 threads per head, shuffle-merged
    int h = t >> 2, sub = t & 3;
    float adst = a_dst[d * IN_HEAD + h];
    float m = -1e30f, den = 0.f;
    for (int i = sub; i < deg; i += 4) {
        int e = elist[beg + i];
        int s = (e < NE) ? es[e] : d;
        float l = a_src[s * IN_HEAD + h] + adst;
        l = l > 0.f ? l : NEG_SLOPE * l;
        if (l > m) { den = den * __expf(m - l) + 1.f; m = l; }
        else den += __expf(l - m);
    }
#pragma unroll
    for (int o = 1; o <= 2; o <<= 1) {
        float mo = __shfl_xor(m, o);
        float dno = __shfl_xor(den, o);
        float mn = fmaxf(m, mo);
        den = den * __expf(m - mn) + dno * __expf(mo - mn);
        m = mn;
    }
    float dinv = 1.f / (den + EPS_A);

    float acc[16];
#pragma unroll
    for (int i = 0; i < 16; ++i) acc[i] = 0.f;

    for (int c0 = 0; c0 < deg; c0 += 256) {
        int cn = min(deg - c0, 256);
        __syncthreads();
        if (t < cn) {
            int e = elist[beg + c0 + t];
            src_s[t] = (e < NE) ? es[e] : d;
        }
        __syncthreads();
        for (int i = 0; i < cn; ++i) {
            int s = src_s[i];
            float l = a_src[s * IN_HEAD + h] + adst;
            l = l > 0.f ? l : NEG_SLOPE * l;
            float alpha = __expf(l - m) * dinv;
            const bf16* Hrow = H1 + (size_t)s * F1 + t * 16;
            bf16x8 v0 = *(const bf16x8*)Hrow;
            bf16x8 v1 = *(const bf16x8*)(Hrow + 8);
#pragma unroll
            for (int j = 0; j < 8; ++j) {
                acc[j]     += alpha * (float)v0[j];
                acc[8 + j] += alpha * (float)v1[j];
            }
        }
    }
#pragma unroll
    for (int j = 0; j < 16; ++j) {
        float v = acc[j] + b1[t * 16 + j];
        acc[j] = v > 0.f ? v : (__expf(v) - 1.f);   // ELU
    }
    bf16x8 o0, o1;
#pragma unroll
    for (int j = 0; j < 8; ++j) { o0[j] = (bf16)acc[j]; o1[j] = (bf16)acc[8 + j]; }
    *(bf16x8*)(h_elu + (size_t)d * F1 + t * 16) = o0;
    *(bf16x8*)(h_elu + (size_t)d * F1 + t * 16 + 8) = o1;
}

// ------- fold 4 bf16 z-partials -> H2 fp32, fused att2 dots ----------------
// block per node; 192 threads, t<160 active: t owns f32x4 at col t*4,
// head h = t>>5 (cols within head: (t&31)*4). 32-lane shuffle reduce.
__global__ __launch_bounds__(192)
void fold2_kernel(const bf16* __restrict__ Hp,
                  const float* __restrict__ as2, const float* __restrict__ ad2,
                  float* __restrict__ H2,
                  float* __restrict__ a_src, float* __restrict__ a_dst) {
    int n = blockIdx.x, t = threadIdx.x;
    if (t >= 160) return;
    int h = t >> 5;
    f32x4 sum = {};
#pragma unroll
    for (int z = 0; z < 4; ++z) {
        bf16x4 v = *(const bf16x4*)(Hp + (size_t)z * N_NODES * F2 + (size_t)n * F2 + t * 4);
        sum[0] += (float)v[0]; sum[1] += (float)v[1];
        sum[2] += (float)v[2]; sum[3] += (float)v[3];
    }
    *(f32x4*)(H2 + (size_t)n * F2 + t * 4) = sum;
    f32x4 ws = *(const f32x4*)(as2 + t * 4);   // as2[h][ (t&31)*4 ] == as2 + t*4
    f32x4 wd = *(const f32x4*)(ad2 + t * 4);
    float s = sum[0] * ws[0] + sum[1] * ws[1] + sum[2] * ws[2] + sum[3] * ws[3];
    float d = sum[0] * wd[0] + sum[1] * wd[1] + sum[2] * wd[2] + sum[3] * wd[3];
#pragma unroll
    for (int o = 1; o <= 16; o <<= 1) {       // xor stays within 32-lane half
        s += __shfl_xor(s, o);
        d += __shfl_xor(d, o);
    }
    if ((t & 31) == 0) {
        a_src[n * OUT_HEAD + h] = s;
        a_dst[n * OUT_HEAD + h] = d;
    }
}

// ------- layer-2 softmax stats: thread per (dst,head) over CSR ----------
__global__ void stats2_kernel(const int* __restrict__ es,
                              const int* __restrict__ row_start,
                              const int* __restrict__ elist,
                              const float* __restrict__ a_src,
                              const float* __restrict__ a_dst,
                              float* __restrict__ m2, float* __restrict__ dinv2) {
    int id = blockIdx.x * 256 + threadIdx.x;
    if (id >= N_NODES * OUT_HEAD) return;
    int d = id / OUT_HEAD, h = id - d * OUT_HEAD;
    int beg = row_start[d], deg = row_start[d + 1] - beg;
    float adst = a_dst[id];
    float m = -1e30f, den = 0.f;
    for (int i = 0; i < deg; ++i) {
        int e = elist[beg + i];
        int s = (e < NE) ? es[e] : d;
        float l = a_src[s * OUT_HEAD + h] + adst;
        l = l > 0.f ? l : NEG_SLOPE * l;
        if (l > m) { den = den * __expf(m - l) + 1.f; m = l; }
        else den += __expf(l - m);
    }
    m2[id] = m;
    dinv2[id] = 1.f / (den + EPS_A);
}

// ------- beta[s][h] = sum over edges with src s of alpha2[e][h] ----------
__global__ void beta_kernel(const int* __restrict__ es, const int* __restrict__ ed,
                            const float* __restrict__ a_src, const float* __restrict__ a_dst,
                            const float* __restrict__ m2, const float* __restrict__ dinv2,
                            float* __restrict__ beta) {
    int id = blockIdx.x * 256 + threadIdx.x;
    if (id >= E_TOT * OUT_HEAD) return;
    int e = id / OUT_HEAD, h = id - e * OUT_HEAD;
    int s = (e < NE) ? es[e] : (e - NE);
    int d = (e < NE) ? ed[e] : (e - NE);
    float l = a_src[s * OUT_HEAD + h] + a_dst[d * OUT_HEAD + h];
    l = l > 0.f ? l : NEG_SLOPE * l;
    float alpha = __expf(l - m2[d * OUT_HEAD + h]) * dinv2[d * OUT_HEAD + h];
    atomicAdd(&beta[s * OUT_HEAD + h], alpha);
}

// ------- total[c] = sum_s sum_h beta[s,h]H2[s,h*128+c]; 8-way stripes -------
__global__ __launch_bounds__(256)
void wsum_kernel(const float* __restrict__ H2, const float* __restrict__ beta,
                 float* __restrict__ acc_out) {
    __shared__ float buf[F2];
    int t = threadIdx.x;
    int n0 = blockIdx.x * 32;
    int h = t >> 5;
    float a0 = 0.f, a1 = 0.f, a2 = 0.f, a3 = 0.f;
    if (t < 160) {
        for (int i = 0; i < 32; ++i) {
            int s = n0 + i;
            float bh = beta[s * OUT_HEAD + h];
            f32x4 v = *(const f32x4*)(H2 + (size_t)s * F2 + t * 4);
            a0 += bh * v[0]; a1 += bh * v[1];
            a2 += bh * v[2]; a3 += bh * v[3];
        }
        buf[t * 4 + 0] = a0; buf[t * 4 + 1] = a1;
        buf[t * 4 + 2] = a2; buf[t * 4 + 3] = a3;
    }
    __syncthreads();
    if (t < OUT_FEAT) {
        float s = 0.f;
#pragma unroll
        for (int hh = 0; hh < OUT_HEAD; ++hh) s += buf[hh * OUT_FEAT + t];
        atomicAdd(&acc_out[(blockIdx.x & 7) * OUT_FEAT + t], s);
    }
}

// ---------------- final: fold stripes, scale, +b2, tanh ----------------
__global__ void tanh_kernel(const float* __restrict__ acc_out,
                            const float* __restrict__ b2, float* __restrict__ out) {
    int c = threadIdx.x;
    float tot = 0.f;
#pragma unroll
    for (int k = 0; k < 8; ++k) tot += acc_out[k * OUT_FEAT + c];
    out[c] = tanhf(tot * (1.f / (OUT_HEAD * (float)N_NODES)) + b2[c]);
}

// ---------------- launch ----------------
extern "C" void kernel_launch(void* const* d_in, const int* in_sizes, int n_in,
                              void* d_out, int out_size, void* d_ws, size_t ws_size,
                              hipStream_t stream) {
    const float* x        = (const float*)d_in[0];
    const int*   ei       = (const int*)d_in[1];
    const float* W1       = (const float*)d_in[2];
    const float* att_src1 = (const float*)d_in[3];
    const float* att_dst1 = (const float*)d_in[4];
    const float* b1       = (const float*)d_in[5];
    const float* W2       = (const float*)d_in[6];
    const float* att_src2 = (const float*)d_in[7];
    const float* att_dst2 = (const float*)d_in[8];
    const float* b2       = (const float*)d_in[9];
    float* out = (float*)d_out;

    const int* esrc = ei;
    const int* edst = ei + NE;

    // workspace carve (~86 MB)
    char* p = (char*)d_ws;
    auto bump = [&](size_t bytes) {
        void* r = (void*)p;
        p += (bytes + 255) & ~(size_t)255;
        return r;
    };
    bf16*  H1     = (bf16*)bump((size_t)N_NODES * F1 * 2);        // 32 MB
    bf16*  h_elu  = (bf16*)bump((size_t)N_NODES * F1 * 2);        // 32 MB
    float* H2     = (float*)bump((size_t)N_NODES * F2 * 4);       // 10.5 MB
    bf16*  xb     = (bf16*)bump((size_t)N_NODES * IN_FEAT * 2);   // 2 MB
    bf16*  W1T    = (bf16*)bump((size_t)F1 * IN_FEAT * 2);        // 2 MB
    bf16*  W2T    = (bf16*)bump((size_t)F2 * F1 * 2);             // 5 MB
    bf16*  w1s    = (bf16*)bump((size_t)IN_FEAT * IN_HEAD * 2);
    bf16*  w1d    = (bf16*)bump((size_t)IN_FEAT * IN_HEAD * 2);
    float* a_src1 = (float*)bump((size_t)N_NODES * IN_HEAD * 4);
    float* a_dst1 = (float*)bump((size_t)N_NODES * IN_HEAD * 4);
    float* a_src2 = (float*)bump((size_t)N_NODES * OUT_HEAD * 4);
    float* a_dst2 = (float*)bump((size_t)N_NODES * OUT_HEAD * 4);
    float* m2     = (float*)bump((size_t)N_NODES * OUT_HEAD * 4);
    float* dinv2  = (float*)bump((size_t)N_NODES * OUT_HEAD * 4);
    int*   row_start = (int*)bump((N_NODES + 1) * 4);
    int*   cursor = (int*)bump(N_NODES * 4);
    int*   elist  = (int*)bump(E_TOT * 4);
    // zeroed region: counts | beta | acc_out (one contiguous memset)
    int*   counts = (int*)bump(N_NODES * 4 + N_NODES * OUT_HEAD * 4 + 8 * OUT_FEAT * 4);
    float* beta    = (float*)((char*)counts + N_NODES * 4);
    float* acc_out = beta + N_NODES * OUT_HEAD;
    // GEMM2 bf16 z-partials alias the H1 region (H1 dead after agg1):
    // 4 * 4096*640*2 B = 21 MB <= 32 MB.
    bf16* Hp = H1;

    hipMemsetAsync(counts, 0,
                   N_NODES * 4 + N_NODES * OUT_HEAD * 4 + 8 * OUT_FEAT * 4, stream);

    // CSR
    hist_kernel<<<(E_TOT + 255) / 256, 256, 0, stream>>>(edst, counts);
    scan_kernel<<<1, 256, 0, stream>>>(counts, row_start, cursor);
    scatter_kernel<<<(E_TOT + 255) / 256, 256, 0, stream>>>(edst, cursor, elist);

    // operand prep (merged)
    prep_kernel<<<PB_X + PB_W1 + PB_W2 + 64, 256, 0, stream>>>(
        x, xb, W1, W1T, W2, W2T, att_src1, att_dst1, w1s, w1d);

    // layer 1
    gemm128_kernel<1, false, bf16>
        <<<dim3(F1 / 128, N_NODES / 128, 1), 256, 0, stream>>>(
        xb, W1T, H1, N_NODES, F1, IN_FEAT);
    gemv1_kernel<<<N_NODES / 4, 256, 0, stream>>>(x, w1s, w1d, a_src1, a_dst1);
    agg1_kernel<<<N_NODES, 256, 0, stream>>>(
        esrc, row_start, elist, a_src1, a_dst1, H1, b1, h_elu);

    // layer 2: z-partials (plain bf16 stores) + fused fold/att2
    gemm128_kernel<4, true, bf16><<<640, 256, 0, stream>>>(
        h_elu, W2T, Hp, N_NODES, F2, F1);
    fold2_kernel<<<N_NODES, 192, 0, stream>>>(
        Hp, att_src2, att_dst2, H2, a_src2, a_dst2);
    stats2_kernel<<<(N_NODES * OUT_HEAD + 255) / 256, 256, 0, stream>>>(
        esrc, row_start, elist, a_src2, a_dst2, m2, dinv2);
    beta_kernel<<<(E_TOT * OUT_HEAD + 255) / 256, 256, 0, stream>>>(
        esrc, edst, a_src2, a_dst2, m2, dinv2, beta);
    wsum_kernel<<<N_NODES / 32, 256, 0, stream>>>(H2, beta, acc_out);

    // final
    tanh_kernel<<<1, OUT_FEAT, 0, stream>>>(acc_out, b2, out);
}

// Round 8
// 245.294 us; speedup vs baseline: 1.5294x; 1.0337x over previous
//
#include <hip/hip_runtime.h>
#include <hip/hip_bf16.h>

// ---------------- problem constants ----------------
#define N_NODES 4096
#define NE      32768           // raw edges
#define E_TOT   (NE + N_NODES)  // + self loops = 36864
#define IN_FEAT 256
#define HID     64
#define IN_HEAD 64
#define F1      4096            // IN_HEAD*HID
#define OUT_HEAD 5
#define OUT_FEAT 128
#define F2      640             // OUT_HEAD*OUT_FEAT
#define NEG_SLOPE 0.2f
#define EPS_A   1e-16f

typedef __bf16 bf16;
typedef bf16 bf16x8 __attribute__((ext_vector_type(8)));
typedef bf16 bf16x4 __attribute__((ext_vector_type(4)));
typedef float f32x4 __attribute__((ext_vector_type(4)));

// async global->LDS, 16B per lane; lds base must be wave-uniform (m104/m108)
__device__ inline void async_cp16(bf16* lds, const bf16* g) {
    __builtin_amdgcn_global_load_lds(
        (const __attribute__((address_space(1))) unsigned int*)g,
        (__attribute__((address_space(3))) unsigned int*)lds, 16, 0, 0);
}

// ---------------- CSR build ----------------
__global__ void hist_kernel(const int* __restrict__ edst, int* counts) {
    int e = blockIdx.x * 256 + threadIdx.x;
    if (e >= E_TOT) return;
    int d = (e < NE) ? edst[e] : (e - NE);
    atomicAdd(&counts[d], 1);
}

__global__ void scan_kernel(const int* __restrict__ counts,
                            int* __restrict__ row_start, int* __restrict__ cursor) {
    __shared__ int part[256];
    __shared__ int pre[257];
    int t = threadIdx.x;
    int base = t * 16;
    int local[16];
    int s = 0;
#pragma unroll
    for (int i = 0; i < 16; ++i) { local[i] = s; s += counts[base + i]; }
    part[t] = s;
    __syncthreads();
    if (t == 0) {
        int r = 0;
        for (int i = 0; i < 256; ++i) { pre[i] = r; r += part[i]; }
        pre[256] = r;
    }
    __syncthreads();
    int off = pre[t];
#pragma unroll
    for (int i = 0; i < 16; ++i) {
        int v = off + local[i];
        row_start[base + i] = v;
        cursor[base + i] = v;
    }
    if (t == 0) row_start[N_NODES] = pre[256];
}

__global__ void scatter_kernel(const int* __restrict__ edst,
                               int* cursor, int* __restrict__ elist) {
    int e = blockIdx.x * 256 + threadIdx.x;
    if (e >= E_TOT) return;
    int d = (e < NE) ? edst[e] : (e - NE);
    int slot = atomicAdd(&cursor[d], 1);
    elist[slot] = e;
}

// ------------- merged operand prep: tobf16(x) | W1^T | W2^T | att-fold ------
#define PB_X   512
#define PB_W1  1024
#define PB_W2  2560
__global__ __launch_bounds__(256)
void prep_kernel(const float* __restrict__ x, bf16* __restrict__ xb,
                 const float* __restrict__ W1, bf16* __restrict__ W1T,
                 const float* __restrict__ W2, bf16* __restrict__ W2T,
                 const float* __restrict__ as1, const float* __restrict__ ad1,
                 bf16* __restrict__ w1s, bf16* __restrict__ w1d) {
    __shared__ float tile[32][33];
    int b = blockIdx.x, t = threadIdx.x;
    if (b < PB_X) {
        int i = b * 256 + t;
        f32x4 a = *(const f32x4*)(x + (size_t)i * 8);
        f32x4 c = *(const f32x4*)(x + (size_t)i * 8 + 4);
        bf16x8 r;
        r[0] = (bf16)a[0]; r[1] = (bf16)a[1]; r[2] = (bf16)a[2]; r[3] = (bf16)a[3];
        r[4] = (bf16)c[0]; r[5] = (bf16)c[1]; r[6] = (bf16)c[2]; r[7] = (bf16)c[3];
        *(bf16x8*)(xb + (size_t)i * 8) = r;
    } else if (b < PB_X + PB_W1 + PB_W2) {
        const float* S; bf16* D; int R, C, gx, gy;
        if (b < PB_X + PB_W1) {
            int bb = b - PB_X;                    // W1: 256 x 4096
            S = W1; D = W1T; R = IN_FEAT; C = F1;
            gx = bb % (F1 / 32); gy = bb / (F1 / 32);
        } else {
            int bb = b - PB_X - PB_W1;            // W2: 4096 x 640
            S = W2; D = W2T; R = F1; C = F2;
            gx = bb % (F2 / 32); gy = bb / (F2 / 32);
        }
        int tx = t & 31, ty = t >> 5;
        int c0 = gx * 32, r0 = gy * 32;
#pragma unroll
        for (int i = 0; i < 4; ++i)
            tile[ty + i * 8][tx] = S[(size_t)(r0 + ty + i * 8) * C + c0 + tx];
        __syncthreads();
#pragma unroll
        for (int i = 0; i < 4; ++i)
            D[(size_t)(c0 + ty + i * 8) * R + r0 + tx] = (bf16)tile[tx][ty + i * 8];
    } else {
        int id = (b - PB_X - PB_W1 - PB_W2) * 256 + t;  // 16384 = 256k x 64h
        int k = id >> 6, h = id & 63;
        const float* wrow = W1 + (size_t)k * F1 + h * HID;
        const float* a1 = as1 + h * HID;
        const float* a2 = ad1 + h * HID;
        float s = 0.f, d = 0.f;
#pragma unroll 8
        for (int c = 0; c < HID; ++c) {
            float w = wrow[c];
            s += w * a1[c];
            d += w * a2[c];
        }
        w1s[id] = (bf16)s;
        w1d[id] = (bf16)d;
    }
}

// ---------------- MFMA GEMM: C[M,N] = A[M,K] @ BT[N,K]^T ----------------
// BM=BN=128, BK=64; XOR-swizzled LDS (0 bank conflicts, verified r4).
// SWZ: XCD-grouped 1D grid for GEMM2 (FETCH 147->24 MB, verified r6).
// SPLITK>1: z-partials to separate buffers, plain stores (r7: killed the
// 68us atomic epilogue).
template <int SPLITK, bool SWZ, typename TC>
__global__ __launch_bounds__(256)
void gemm128_kernel(const bf16* __restrict__ A, const bf16* __restrict__ BT,
                    TC* __restrict__ C, int M, int N, int K) {
    __shared__ bf16 As[128][64];
    __shared__ bf16 Bs[128][64];
    const int tid  = threadIdx.x;
    const int wave = tid >> 6, lane = tid & 63;
    const int quad = lane >> 4, lr = lane & 15;
    int nb, mb, zb;
    if constexpr (SWZ) {
        int bid = blockIdx.x;
        int xx = bid & 7, q = bid >> 3;
        int gp = q / 5; nb = q - gp * 5;
        int g = gp * 8 + xx;
        mb = g >> 2; zb = g & 3;
    } else {
        nb = blockIdx.x; mb = blockIdx.y; zb = blockIdx.z;
    }
    const int m0 = mb * 128, n0 = nb * 128;
    const int kchunk = K / SPLITK;
    const int kbeg = zb * kchunk;
    const int wm = (wave >> 1) * 64;
    const int wn = (wave & 1) * 64;
    TC* Cz = C + (size_t)zb * M * N;

    const int srow = lane >> 3;
    const int scol = ((lane & 7) ^ srow) * 8;
    const int xk = lr & 7;

    f32x4 acc[4][4] = {};

    for (int kk = 0; kk < kchunk; kk += 64) {
        int k0 = kbeg + kk;
#pragma unroll
        for (int c = 0; c < 4; ++c) {
            int r = wave * 32 + c * 8;
            async_cp16(&As[r][0], A + (size_t)(m0 + r + srow) * K + k0 + scol);
            async_cp16(&Bs[r][0], BT + (size_t)(n0 + r + srow) * K + k0 + scol);
        }
        __syncthreads();

#pragma unroll
        for (int ks = 0; ks < 2; ++ks) {
            int ch = ((ks * 4 + quad) ^ xk) * 8;
            bf16x8 af[4], bfr[4];
#pragma unroll
            for (int mt = 0; mt < 4; ++mt)
                af[mt] = *(const bf16x8*)(&As[wm + mt * 16 + lr][ch]);
#pragma unroll
            for (int nt = 0; nt < 4; ++nt)
                bfr[nt] = *(const bf16x8*)(&Bs[wn + nt * 16 + lr][ch]);
#pragma unroll
            for (int mt = 0; mt < 4; ++mt)
#pragma unroll
                for (int nt = 0; nt < 4; ++nt)
                    acc[mt][nt] = __builtin_amdgcn_mfma_f32_16x16x32_bf16(
                        af[mt], bfr[nt], acc[mt][nt], 0, 0, 0);
        }
        __syncthreads();
    }

#pragma unroll
    for (int mt = 0; mt < 4; ++mt)
#pragma unroll
        for (int nt = 0; nt < 4; ++nt) {
            int row0 = m0 + wm + mt * 16 + quad * 4;
            int col = n0 + wn + nt * 16 + lr;
#pragma unroll
            for (int r = 0; r < 4; ++r)
                Cz[(size_t)(row0 + r) * N + col] = (TC)acc[mt][nt][r];
        }
}

// a_src1[n][h] = x[n,:] @ w1s[:,h]  — wave per node, lane = head
__global__ __launch_bounds__(256)
void gemv1_kernel(const float* __restrict__ x,
                  const bf16* __restrict__ w1s, const bf16* __restrict__ w1d,
                  float* __restrict__ a_src, float* __restrict__ a_dst) {
    int wave = threadIdx.x >> 6, lane = threadIdx.x & 63;
    int n = blockIdx.x * 4 + wave;
    const float* xr = x + (size_t)n * IN_FEAT;
    float s = 0.f, d = 0.f;
    for (int k0 = 0; k0 < IN_FEAT; k0 += 4) {
        f32x4 xv = *(const f32x4*)(xr + k0);
#pragma unroll
        for (int j = 0; j < 4; ++j) {
            float xs = xv[j];
            s += xs * (float)w1s[(k0 + j) * IN_HEAD + lane];
            d += xs * (float)w1d[(k0 + j) * IN_HEAD + lane];
        }
    }
    a_src[n * IN_HEAD + lane] = s;
    a_dst[n * IN_HEAD + lane] = d;
}

// ------- layer-1 aggregation, FEATURE-SLICED + XCD-PINNED ------------------
// grid = 4096 dst x 8 slices, 64 threads (1 wave). bid&7 = slice -> XCD
// (bid%8 round-robin, evidenced r6): XCD x only touches H1 cols
// [512x,512x+512) = 4 MB = its L2 capacity, so the random gather hits L2
// after the first touch (r7: FETCH 142 MB from full-row gathers).
// Lane owns 8 contiguous features; head-in-slice = lane>>3 (8 lanes/head).
__global__ __launch_bounds__(64)
void agg1_kernel(const int* __restrict__ es, const int* __restrict__ row_start,
                 const int* __restrict__ elist,
                 const float* __restrict__ a_src, const float* __restrict__ a_dst,
                 const bf16* __restrict__ H1, const float* __restrict__ b1,
                 bf16* __restrict__ h_elu) {
    int bid = blockIdx.x;
    int c = bid & 7;            // feature slice / XCD
    int d = bid >> 3;           // dst node
    int lane = threadIdx.x;
    int gh = c * 8 + (lane >> 3);   // global head for this lane
    int sub = lane & 7;
    int beg = row_start[d], deg = row_start[d + 1] - beg;
    float adst = a_dst[d * IN_HEAD + gh];

    // online softmax stats: 8 lanes per head, strided, shuffle-merged
    float m = -1e30f, den = 0.f;
    for (int i = sub; i < deg; i += 8) {
        int e = elist[beg + i];
        int s = (e < NE) ? es[e] : d;
        float l = a_src[s * IN_HEAD + gh] + adst;
        l = l > 0.f ? l : NEG_SLOPE * l;
        if (l > m) { den = den * __expf(m - l) + 1.f; m = l; }
        else den += __expf(l - m);
    }
#pragma unroll
    for (int o = 1; o <= 4; o <<= 1) {   // xor 1,2,4 stays in 8-lane group
        float mo = __shfl_xor(m, o);
        float dno = __shfl_xor(den, o);
        float mn = fmaxf(m, mo);
        den = den * __expf(m - mn) + dno * __expf(mo - mn);
        m = mn;
    }
    float dinv = 1.f / (den + EPS_A);

    // gather: lane reads its 16B of the slice per edge (1 KB/wave/edge)
    int fbase = c * 512 + lane * 8;
    float acc[8] = {};
    for (int i = 0; i < deg; ++i) {
        int e = elist[beg + i];              // wave-uniform -> broadcast
        int s = (e < NE) ? es[e] : d;
        float l = a_src[s * IN_HEAD + gh] + adst;
        l = l > 0.f ? l : NEG_SLOPE * l;
        float alpha = __expf(l - m) * dinv;
        bf16x8 v = *(const bf16x8*)(H1 + (size_t)s * F1 + fbase);
#pragma unroll
        for (int j = 0; j < 8; ++j) acc[j] += alpha * (float)v[j];
    }

    bf16x8 o;
#pragma unroll
    for (int j = 0; j < 8; ++j) {
        float v = acc[j] + b1[fbase + j];
        o[j] = (bf16)(v > 0.f ? v : (__expf(v) - 1.f));   // ELU
    }
    *(bf16x8*)(h_elu + (size_t)d * F1 + fbase) = o;
}

// ------- fold 4 bf16 z-partials -> H2 fp32, fused att2 dots ----------------
__global__ __launch_bounds__(192)
void fold2_kernel(const bf16* __restrict__ Hp,
                  const float* __restrict__ as2, const float* __restrict__ ad2,
                  float* __restrict__ H2,
                  float* __restrict__ a_src, float* __restrict__ a_dst) {
    int n = blockIdx.x, t = threadIdx.x;
    if (t >= 160) return;
    int h = t >> 5;
    f32x4 sum = {};
#pragma unroll
    for (int z = 0; z < 4; ++z) {
        bf16x4 v = *(const bf16x4*)(Hp + (size_t)z * N_NODES * F2 + (size_t)n * F2 + t * 4);
        sum[0] += (float)v[0]; sum[1] += (float)v[1];
        sum[2] += (float)v[2]; sum[3] += (float)v[3];
    }
    *(f32x4*)(H2 + (size_t)n * F2 + t * 4) = sum;
    f32x4 ws = *(const f32x4*)(as2 + t * 4);
    f32x4 wd = *(const f32x4*)(ad2 + t * 4);
    float s = sum[0] * ws[0] + sum[1] * ws[1] + sum[2] * ws[2] + sum[3] * ws[3];
    float d = sum[0] * wd[0] + sum[1] * wd[1] + sum[2] * wd[2] + sum[3] * wd[3];
#pragma unroll
    for (int o = 1; o <= 16; o <<= 1) {
        s += __shfl_xor(s, o);
        d += __shfl_xor(d, o);
    }
    if ((t & 31) == 0) {
        a_src[n * OUT_HEAD + h] = s;
        a_dst[n * OUT_HEAD + h] = d;
    }
}

// ------- layer-2 softmax stats: thread per (dst,head) over CSR ----------
__global__ void stats2_kernel(const int* __restrict__ es,
                              const int* __restrict__ row_start,
                              const int* __restrict__ elist,
                              const float* __restrict__ a_src,
                              const float* __restrict__ a_dst,
                              float* __restrict__ m2, float* __restrict__ dinv2) {
    int id = blockIdx.x * 256 + threadIdx.x;
    if (id >= N_NODES * OUT_HEAD) return;
    int d = id / OUT_HEAD, h = id - d * OUT_HEAD;
    int beg = row_start[d], deg = row_start[d + 1] - beg;
    float adst = a_dst[id];
    float m = -1e30f, den = 0.f;
    for (int i = 0; i < deg; ++i) {
        int e = elist[beg + i];
        int s = (e < NE) ? es[e] : d;
        float l = a_src[s * OUT_HEAD + h] + adst;
        l = l > 0.f ? l : NEG_SLOPE * l;
        if (l > m) { den = den * __expf(m - l) + 1.f; m = l; }
        else den += __expf(l - m);
    }
    m2[id] = m;
    dinv2[id] = 1.f / (den + EPS_A);
}

// ------- beta[s][h] = sum over edges with src s of alpha2[e][h] ----------
__global__ void beta_kernel(const int* __restrict__ es, const int* __restrict__ ed,
                            const float* __restrict__ a_src, const float* __restrict__ a_dst,
                            const float* __restrict__ m2, const float* __restrict__ dinv2,
                            float* __restrict__ beta) {
    int id = blockIdx.x * 256 + threadIdx.x;
    if (id >= E_TOT * OUT_HEAD) return;
    int e = id / OUT_HEAD, h = id - e * OUT_HEAD;
    int s = (e < NE) ? es[e] : (e - NE);
    int d = (e < NE) ? ed[e] : (e - NE);
    float l = a_src[s * OUT_HEAD + h] + a_dst[d * OUT_HEAD + h];
    l = l > 0.f ? l : NEG_SLOPE * l;
    float alpha = __expf(l - m2[d * OUT_HEAD + h]) * dinv2[d * OUT_HEAD + h];
    atomicAdd(&beta[s * OUT_HEAD + h], alpha);
}

// ------- total[c] = sum_s sum_h beta[s,h]H2[s,h*128+c]; 8-way stripes -------
__global__ __launch_bounds__(256)
void wsum_kernel(const float* __restrict__ H2, const float* __restrict__ beta,
                 float* __restrict__ acc_out) {
    __shared__ float buf[F2];
    int t = threadIdx.x;
    int n0 = blockIdx.x * 32;
    int h = t >> 5;
    float a0 = 0.f, a1 = 0.f, a2 = 0.f, a3 = 0.f;
    if (t < 160) {
        for (int i = 0; i < 32; ++i) {
            int s = n0 + i;
            float bh = beta[s * OUT_HEAD + h];
            f32x4 v = *(const f32x4*)(H2 + (size_t)s * F2 + t * 4);
            a0 += bh * v[0]; a1 += bh * v[1];
            a2 += bh * v[2]; a3 += bh * v[3];
        }
        buf[t * 4 + 0] = a0; buf[t * 4 + 1] = a1;
        buf[t * 4 + 2] = a2; buf[t * 4 + 3] = a3;
    }
    __syncthreads();
    if (t < OUT_FEAT) {
        float s = 0.f;
#pragma unroll
        for (int hh = 0; hh < OUT_HEAD; ++hh) s += buf[hh * OUT_FEAT + t];
        atomicAdd(&acc_out[(blockIdx.x & 7) * OUT_FEAT + t], s);
    }
}

// ---------------- final: fold stripes, scale, +b2, tanh ----------------
__global__ void tanh_kernel(const float* __restrict__ acc_out,
                            const float* __restrict__ b2, float* __restrict__ out) {
    int c = threadIdx.x;
    float tot = 0.f;
#pragma unroll
    for (int k = 0; k < 8; ++k) tot += acc_out[k * OUT_FEAT + c];
    out[c] = tanhf(tot * (1.f / (OUT_HEAD * (float)N_NODES)) + b2[c]);
}

// ---------------- launch ----------------
extern "C" void kernel_launch(void* const* d_in, const int* in_sizes, int n_in,
                              void* d_out, int out_size, void* d_ws, size_t ws_size,
                              hipStream_t stream) {
    const float* x        = (const float*)d_in[0];
    const int*   ei       = (const int*)d_in[1];
    const float* W1       = (const float*)d_in[2];
    const float* att_src1 = (const float*)d_in[3];
    const float* att_dst1 = (const float*)d_in[4];
    const float* b1       = (const float*)d_in[5];
    const float* W2       = (const float*)d_in[6];
    const float* att_src2 = (const float*)d_in[7];
    const float* att_dst2 = (const float*)d_in[8];
    const float* b2       = (const float*)d_in[9];
    float* out = (float*)d_out;

    const int* esrc = ei;
    const int* edst = ei + NE;

    // workspace carve (~86 MB)
    char* p = (char*)d_ws;
    auto bump = [&](size_t bytes) {
        void* r = (void*)p;
        p += (bytes + 255) & ~(size_t)255;
        return r;
    };
    bf16*  H1     = (bf16*)bump((size_t)N_NODES * F1 * 2);        // 32 MB
    bf16*  h_elu  = (bf16*)bump((size_t)N_NODES * F1 * 2);        // 32 MB
    float* H2     = (float*)bump((size_t)N_NODES * F2 * 4);       // 10.5 MB
    bf16*  xb     = (bf16*)bump((size_t)N_NODES * IN_FEAT * 2);   // 2 MB
    bf16*  W1T    = (bf16*)bump((size_t)F1 * IN_FEAT * 2);        // 2 MB
    bf16*  W2T    = (bf16*)bump((size_t)F2 * F1 * 2);             // 5 MB
    bf16*  w1s    = (bf16*)bump((size_t)IN_FEAT * IN_HEAD * 2);
    bf16*  w1d    = (bf16*)bump((size_t)IN_FEAT * IN_HEAD * 2);
    float* a_src1 = (float*)bump((size_t)N_NODES * IN_HEAD * 4);
    float* a_dst1 = (float*)bump((size_t)N_NODES * IN_HEAD * 4);
    float* a_src2 = (float*)bump((size_t)N_NODES * OUT_HEAD * 4);
    float* a_dst2 = (float*)bump((size_t)N_NODES * OUT_HEAD * 4);
    float* m2     = (float*)bump((size_t)N_NODES * OUT_HEAD * 4);
    float* dinv2  = (float*)bump((size_t)N_NODES * OUT_HEAD * 4);
    int*   row_start = (int*)bump((N_NODES + 1) * 4);
    int*   cursor = (int*)bump(N_NODES * 4);
    int*   elist  = (int*)bump(E_TOT * 4);
    // zeroed region: counts | beta | acc_out (one contiguous memset)
    int*   counts = (int*)bump(N_NODES * 4 + N_NODES * OUT_HEAD * 4 + 8 * OUT_FEAT * 4);
    float* beta    = (float*)((char*)counts + N_NODES * 4);
    float* acc_out = beta + N_NODES * OUT_HEAD;
    // GEMM2 bf16 z-partials alias the H1 region (H1 dead after agg1)
    bf16* Hp = H1;

    hipMemsetAsync(counts, 0,
                   N_NODES * 4 + N_NODES * OUT_HEAD * 4 + 8 * OUT_FEAT * 4, stream);

    // CSR
    hist_kernel<<<(E_TOT + 255) / 256, 256, 0, stream>>>(edst, counts);
    scan_kernel<<<1, 256, 0, stream>>>(counts, row_start, cursor);
    scatter_kernel<<<(E_TOT + 255) / 256, 256, 0, stream>>>(edst, cursor, elist);

    // operand prep (merged)
    prep_kernel<<<PB_X + PB_W1 + PB_W2 + 64, 256, 0, stream>>>(
        x, xb, W1, W1T, W2, W2T, att_src1, att_dst1, w1s, w1d);

    // layer 1
    gemm128_kernel<1, false, bf16>
        <<<dim3(F1 / 128, N_NODES / 128, 1), 256, 0, stream>>>(
        xb, W1T, H1, N_NODES, F1, IN_FEAT);
    gemv1_kernel<<<N_NODES / 4, 256, 0, stream>>>(x, w1s, w1d, a_src1, a_dst1);
    agg1_kernel<<<N_NODES * 8, 64, 0, stream>>>(
        esrc, row_start, elist, a_src1, a_dst1, H1, b1, h_elu);

    // layer 2: z-partials (plain bf16 stores) + fused fold/att2
    gemm128_kernel<4, true, bf16><<<640, 256, 0, stream>>>(
        h_elu, W2T, Hp, N_NODES, F2, F1);
    fold2_kernel<<<N_NODES, 192, 0, stream>>>(
        Hp, att_src2, att_dst2, H2, a_src2, a_dst2);
    stats2_kernel<<<(N_NODES * OUT_HEAD + 255) / 256, 256, 0, stream>>>(
        esrc, row_start, elist, a_src2, a_dst2, m2, dinv2);
    beta_kernel<<<(E_TOT * OUT_HEAD + 255) / 256, 256, 0, stream>>>(
        esrc, edst, a_src2, a_dst2, m2, dinv2, beta);
    wsum_kernel<<<N_NODES / 32, 256, 0, stream>>>(H2, beta, acc_out);

    // final
    tanh_kernel<<<1, OUT_FEAT, 0, stream>>>(acc_out, b2, out);
}